// Round 11
// baseline (93.909 us; speedup 1.0000x reference)
//
#include <hip/hip_runtime.h>
#include <math.h>

// Problem constants
#define T_STEPS 50
#define NS      2048
#define IND     16
#define HID     128
#define GATES   512
#define RR      8
#define KN      32
#define EPSV    1e-10f

// LSTM MFMA tiling: 512 blocks x 4 rows x 8 waves. Round-6 register recipe
// (natural VGPR=80, no spill, launch_bounds(512,2)) -> at 80 regs TWO 8-wave
// blocks co-reside per CU (4 waves/SIMD), breaking the 1-block phase lock.
// Rounds 7/8 failed this ONLY because launch_bounds(512,4) forced a 128-reg
// cap -> 64v/64a split -> spill storm. Bounds stay (512,2).
#define LROWS   4
#define APAD    168     // padded f16 row stride of the A tile
#define LTH     512     // 8 waves; wave w owns gate cols [16w,16w+16) per group

typedef _Float16 f16x8 __attribute__((ext_vector_type(8)));
typedef _Float16 f16x4 __attribute__((ext_vector_type(4)));
typedef float    f32x4 __attribute__((ext_vector_type(4)));

// Fast activations: raw v_rcp_f32 (1 ULP) instead of precise-div sequence.
__device__ __forceinline__ float rcp_(float x)  { return __builtin_amdgcn_rcpf(x); }
__device__ __forceinline__ float sigm(float x)  { return rcp_(1.0f + __expf(-x)); }
__device__ __forceinline__ float tanhf_(float x){ return 1.0f - 2.0f * rcp_(1.0f + __expf(2.0f * x)); }

__device__ __forceinline__ f16x8 zero8() {
    f16x8 z;
#pragma unroll
    for (int j = 0; j < 8; ++j) z[j] = (_Float16)0.0f;
    return z;
}

// ---------------------------------------------------------------------------
// LSTM via MFMA f16 (round-6 body, 4-row blocks). 4 real rows at M-rows
// {0,4,8,12} of the 16-row tile: C-reg r=0 of every lane is a real cell
// (1 cell/lane -> TRANS per wave halves; no cross-lane redistribution).
// Full-width unpredicated ds_reads (round-9 predication was a regression).
// Weights register-resident (keep-alive asm); x LDS-staged; double-buffered
// sA; one barrier per step. Epilogue writes se (fp32) and se16 (f16).
// ---------------------------------------------------------------------------
__global__ __launch_bounds__(LTH, 2) void lstm_mfma_kernel(
    const float* __restrict__ x,     // (T, NS, IND)
    const float* __restrict__ W_ih,  // (GATES, IND)
    const float* __restrict__ W_hh,  // (GATES, HID)
    const float* __restrict__ b_ih,  // (GATES)
    const float* __restrict__ b_hh,  // (GATES)
    float* __restrict__ se,          // (NS, HID) out fp32
    _Float16* __restrict__ se16)     // (NS, HID) out f16
{
    __shared__ __align__(16) _Float16 sA[2][16][APAD];           // 10.75 KB
    __shared__ __align__(16) _Float16 sX[T_STEPS][LROWS * IND];  // 6.4 KB

    const int tid    = threadIdx.x;
    const int w      = tid >> 6;       // wave 0..7
    const int l      = tid & 63;
    const int lane16 = l & 15;
    const int lgrp   = l >> 4;         // 0..3 (MFMA fragment k-group)
    const int n0     = blockIdx.x * LROWS;

    // ---- prologue: W -> f16 B-fragments in registers (static all 50 steps)
    // B[gg][kf]: gate col gi = 128*gg + 16*w + lane16 ; k = kf*32 + lgrp*8 + j
    // K layout: [x(16) | h(128) | pad(16)]
    f16x8 B[4][5];
    float bias[4];
#pragma unroll
    for (int gg = 0; gg < 4; ++gg) {
        const int gi = 128 * gg + 16 * w + lane16;
        bias[gg] = b_ih[gi] + b_hh[gi];
#pragma unroll
        for (int kf = 0; kf < 5; ++kf) {
            const int k0 = kf * 32 + lgrp * 8;
            f16x8 v;
            if (k0 < 16) {                       // x part -> W_ih
                const float* p = W_ih + gi * IND + k0;
#pragma unroll
                for (int j = 0; j < 8; ++j) v[j] = (_Float16)p[j];
            } else if (k0 >= 144) {              // zero pad
                v = zero8();
            } else {                             // h part -> W_hh
                const float* p = W_hh + gi * HID + (k0 - 16);
#pragma unroll
                for (int j = 0; j < 8; ++j) v[j] = (_Float16)p[j];
            }
            B[gg][kf] = v;
        }
    }
    // Opaque to the optimizer: B cannot be rematerialized -> stays resident.
#pragma unroll
    for (int gg = 0; gg < 4; ++gg)
#pragma unroll
        for (int kf = 0; kf < 5; ++kf)
            asm volatile("" : "+v"(B[gg][kf]));

    // zero both sA buffers (dummy M-rows + K-pad stay zero forever)
    for (int i = tid; i < 2 * 16 * APAD; i += LTH)
        (&sA[0][0][0])[i] = (_Float16)0.0f;

    // stage ALL x for this block's 4 rows, f16 (coalesced, once)
    for (int i = tid; i < T_STEPS * LROWS * IND; i += LTH) {
        const int t = i >> 6, e = i & 63;
        sX[t][e] = (_Float16)x[((size_t)t * NS + n0) * IND + e];
    }
    __syncthreads();
    // x_0: real row r -> M-row 4r, cols 0..15
    if (tid < LROWS * IND) sA[0][4 * (tid >> 4)][tid & 15] = sX[0][tid];
    __syncthreads();

    // lane owns ONE cell: (row lgrp, col 16w+lane16) = C-reg r=0 of M-row 4*lgrp
    float c = 0.f, h = 0.f;

    for (int step = 0; step < T_STEPS; ++step) {
        const int cur = step & 1, nxt = cur ^ 1;

        // A fragments: M-row = lane16 (non-{0,4,8,12} rows read zeros);
        // full-width unpredicated reads (pipeline-friendly)
        f16x8 A[5];
#pragma unroll
        for (int kf = 0; kf < 5; ++kf)
            A[kf] = *(const f16x8*)&sA[cur][lane16][kf * 32 + lgrp * 8];

        _Float16 xv = (_Float16)0.0f;
        if (step + 1 < T_STEPS && tid < LROWS * IND) xv = sX[step + 1][tid];

        f32x4 zi = {bias[0], bias[0], bias[0], bias[0]};
        f32x4 zf = {bias[1], bias[1], bias[1], bias[1]};
        f32x4 zg = {bias[2], bias[2], bias[2], bias[2]};
        f32x4 zo = {bias[3], bias[3], bias[3], bias[3]};
#pragma unroll
        for (int kf = 0; kf < 5; ++kf) {
            zi = __builtin_amdgcn_mfma_f32_16x16x32_f16(A[kf], B[0][kf], zi, 0, 0, 0);
            zf = __builtin_amdgcn_mfma_f32_16x16x32_f16(A[kf], B[1][kf], zf, 0, 0, 0);
            zg = __builtin_amdgcn_mfma_f32_16x16x32_f16(A[kf], B[2][kf], zg, 0, 0, 0);
            zo = __builtin_amdgcn_mfma_f32_16x16x32_f16(A[kf], B[3][kf], zo, 0, 0, 0);
        }

        // cell update on C-reg 0 only (the real row); no cross-lane ops
        c = sigm(zf[0]) * c + sigm(zi[0]) * tanhf_(zg[0]);
        h = sigm(zo[0]) * tanhf_(c);

        // write x_{t+1}, h_{t+1} into the other buffer; one barrier per step
        if (step + 1 < T_STEPS) {
            if (tid < LROWS * IND) sA[nxt][4 * (tid >> 4)][tid & 15] = xv;
            sA[nxt][4 * lgrp][16 + 16 * w + lane16] = (_Float16)h;
        }
        __syncthreads();
    }

    se[(n0 + lgrp) * HID + 16 * w + lane16]   = h;
    se16[(n0 + lgrp) * HID + 16 * w + lane16] = (_Float16)h;
}

// ---------------------------------------------------------------------------
// Kernel 2: precompute sw[n] = se[n].w_att[0:H] and p2[n] = se[n].w_att[H:2H].
// ---------------------------------------------------------------------------
__global__ __launch_bounds__(256) void precompute_kernel(
    const float* __restrict__ se,     // (NS, HID)
    const float* __restrict__ w_att,  // (2H + R)
    float* __restrict__ sw,           // (NS)
    float* __restrict__ p2n)          // (NS)
{
    const int wid  = threadIdx.x >> 6;
    const int lane = threadIdx.x & 63;
    const int n    = blockIdx.x * 4 + wid;

    const float a = se[n * HID + lane];
    const float b = se[n * HID + 64 + lane];
    float d1 = a * w_att[lane]       + b * w_att[64 + lane];
    float d2 = a * w_att[HID + lane] + b * w_att[HID + 64 + lane];
#pragma unroll
    for (int d = 32; d > 0; d >>= 1) {
        d1 += __shfl_xor(d1, d);
        d2 += __shfl_xor(d2, d);
    }
    if (lane == 0) { sw[n] = d1; p2n[n] = d2; }
}

// ---------------------------------------------------------------------------
// Kernel 3: FUSED attention + combine (round-10 exact). Score phase = one 4B
// gather of precomputed sw per neighbor; weighted-sum phase = coalesced
// half-wave f16 row reads. LDS 4.6 KB -> high occupancy.
// ---------------------------------------------------------------------------
__global__ __launch_bounds__(512) void attn_fused_kernel(
    const _Float16* __restrict__ se16,   // (NS, HID) f16
    const float* __restrict__ se,        // (NS, HID) fp32 (residual)
    const int*   __restrict__ neighbors, // (RR, NS, KN)
    const float* __restrict__ rel_num,   // (RR, NS)
    const float* __restrict__ sw,        // (NS) precomputed se.w_nb
    const float* __restrict__ p2n,       // (NS) precomputed se.w_self
    const float* __restrict__ w_att,     // (2H + R)
    const float* __restrict__ b_att,     // (1)
    const float* __restrict__ w_rel,     // (H + R)
    const float* __restrict__ b_rel,     // (1)
    const float* __restrict__ w_fc1,     // (HID)
    const float* __restrict__ b_fc1,     // (1)
    float* __restrict__ out)             // (NS)
{
    __shared__ float srel[RR][HID];      // 4 KB
    __shared__ float srsc[RR];

    const int r    = threadIdx.x >> 6;   // wave = relation 0..7
    const int lane = threadIdx.x & 63;
    const int n    = blockIdx.x;
    const size_t pair = (size_t)r * NS + n;
    const f16x4* se16_4 = (const f16x4*)se16;

    // neighbor indices: lane k (0..31) holds idx_k
    int myidx = 0;
    if (lane < KN) myidx = neighbors[pair * KN + lane];

    // ---- score: one scalar gather per neighbor (zero row -> dot = 0)
    float s = 0.f;
    if (lane < KN) {
        float swv = (myidx != 0) ? sw[myidx - 1] : 0.f;
        s = swv + p2n[n] + w_att[2 * HID + r] + b_att[0];
    }
    float mx = s;
#pragma unroll
    for (int d = 16; d > 0; d >>= 1) mx = fmaxf(mx, __shfl_xor(mx, d, 32));
    float e  = __expf(s - mx);
    float sm = e;
#pragma unroll
    for (int d = 16; d > 0; d >>= 1) sm += __shfl_xor(sm, d, 32);
    float att = e * rcp_(sm);    // valid in lanes 0..31

    // ---- weighted sum: lanes as (k2 = lane>>5, c4 = lane&31)
    const int k2 = lane >> 5;
    const int c4 = lane & 31;
    float ax = 0.f, ay = 0.f, az = 0.f, aw = 0.f;
#pragma unroll
    for (int kk = 0; kk < KN / 2; ++kk) {
        const int   kq = kk * 2 + k2;
        const float av = __shfl(att, kq);
        const int  idq = __shfl(myidx, kq);
        if (idq != 0) {
            f16x4 v = se16_4[(size_t)(idq - 1) * (HID / 4) + c4];
            ax += av * (float)v[0]; ay += av * (float)v[1];
            az += av * (float)v[2]; aw += av * (float)v[3];
        }
    }
    ax += __shfl_xor(ax, 32); ay += __shfl_xor(ay, 32);
    az += __shfl_xor(az, 32); aw += __shfl_xor(aw, 32);

    const float inv = rcp_(rel_num[pair] + EPSV);
    float pr = 0.f;
    if (k2 == 0) {
        ax *= inv; ay *= inv; az *= inv; aw *= inv;
        *(float4*)&srel[r][c4 * 4] = make_float4(ax, ay, az, aw);
        pr = ax * w_rel[c4 * 4] + ay * w_rel[c4 * 4 + 1]
           + az * w_rel[c4 * 4 + 2] + aw * w_rel[c4 * 4 + 3];
    }
#pragma unroll
    for (int d = 16; d > 0; d >>= 1) pr += __shfl_xor(pr, d, 32);
    if (lane == 0) srsc[r] = pr + w_rel[HID + r] + b_rel[0];

    __syncthreads();   // the only block-wide barrier

    if (r == 0) {
        float rs[RR];
        float rmx = -1e30f;
#pragma unroll
        for (int q = 0; q < RR; ++q) {
            rs[q] = srsc[q];
            rmx = fmaxf(rmx, rs[q]);
        }
        float rsm = 0.f;
#pragma unroll
        for (int q = 0; q < RR; ++q) {
            rs[q] = __expf(rs[q] - rmx);
            rsm += rs[q];
        }
        const float invs = rcp_(rsm * (float)RR);

        float u0 = 0.f, u1 = 0.f;
#pragma unroll
        for (int q = 0; q < RR; ++q) {
            u0 += rs[q] * srel[q][lane];
            u1 += rs[q] * srel[q][64 + lane];
        }
        u0 = u0 * invs + se[n * HID + lane];
        u1 = u1 * invs + se[n * HID + 64 + lane];

        float p = u0 * w_fc1[lane] + u1 * w_fc1[64 + lane];
#pragma unroll
        for (int d = 32; d > 0; d >>= 1) p += __shfl_xor(p, d);
        if (lane == 0) out[n] = p + b_fc1[0];
    }
}

// ---------------------------------------------------------------------------
extern "C" void kernel_launch(void* const* d_in, const int* in_sizes, int n_in,
                              void* d_out, int out_size, void* d_ws, size_t ws_size,
                              hipStream_t stream) {
    const float* x      = (const float*)d_in[0];
    const int*   nbrs   = (const int*)  d_in[1];
    const float* relnum = (const float*)d_in[2];
    const float* W_ih   = (const float*)d_in[3];
    const float* W_hh   = (const float*)d_in[4];
    const float* b_ih   = (const float*)d_in[5];
    const float* b_hh   = (const float*)d_in[6];
    const float* w_att  = (const float*)d_in[7];
    const float* b_att  = (const float*)d_in[8];
    const float* w_rel  = (const float*)d_in[9];
    const float* b_rel  = (const float*)d_in[10];
    const float* w_fc1  = (const float*)d_in[11];
    const float* b_fc1  = (const float*)d_in[12];
    float* out = (float*)d_out;

    // workspace: se fp32 (1MB) | se16 f16 (512KB) | sw (8KB) | p2 (8KB)
    float*    se   = (float*)d_ws;
    _Float16* se16 = (_Float16*)(se + (size_t)NS * HID);
    float*    sw   = (float*)(se16 + (size_t)NS * HID);
    float*    p2n  = sw + NS;

    hipLaunchKernelGGL(lstm_mfma_kernel, dim3(NS / LROWS), dim3(LTH), 0, stream,
                       x, W_ih, W_hh, b_ih, b_hh, se, se16);
    hipLaunchKernelGGL(precompute_kernel, dim3(NS / 4), dim3(256), 0, stream,
                       se, w_att, sw, p2n);
    hipLaunchKernelGGL(attn_fused_kernel, dim3(NS), dim3(512), 0, stream,
                       se16, se, nbrs, relnum, sw, p2n, w_att, b_att,
                       w_rel, b_rel, w_fc1, b_fc1, out);
}

// Round 12
// 64.102 us; speedup vs baseline: 1.4650x; 1.4650x over previous
//
#include <hip/hip_runtime.h>
#include <math.h>

// Problem constants
#define T_STEPS 50
#define NS      2048
#define IND     16
#define HID     128
#define GATES   512
#define RR      8
#define KN      32
#define EPSV    1e-10f

// LSTM MFMA tiling (round-6 proven structure): 256 blocks x 8 rows, 8 waves.
#define LROWS   8
#define LTH     512     // 8 waves; wave w owns gate cols [16w,16w+16) per group
#define XPAD    20      // sX row stride (f16): 40B -> conflict-free b64 reads

typedef _Float16 f16x8 __attribute__((ext_vector_type(8)));
typedef _Float16 f16x4 __attribute__((ext_vector_type(4)));
typedef float    f32x4 __attribute__((ext_vector_type(4)));

// Fast activations: raw v_rcp_f32 (1 ULP) instead of precise-div sequence.
__device__ __forceinline__ float rcp_(float x)  { return __builtin_amdgcn_rcpf(x); }
__device__ __forceinline__ float sigm(float x)  { return rcp_(1.0f + __expf(-x)); }
__device__ __forceinline__ float tanhf_(float x){ return 1.0f - 2.0f * rcp_(1.0f + __expf(2.0f * x)); }

// ---------------------------------------------------------------------------
// LSTM via MFMA f16 (round-6 structure, LDS diet).
// - 8 real rows at EVEN M-rows {0,2,...,14}: C-regs 0 and 2 of every lane are
//   real cells (2 cells/lane, zero cross-lane ops).
// - x is OUT of the recurrence tile: all 50 steps staged once in sX (odd
//   M-rows zero), consumed via a 16x16x16 MFMA -> no per-step x load/write.
// - sA is h-only [2][16][128], XOR-swizzled (byte ^= (row&7)<<4) so the
//   16-rows-same-column ds_read_b128 pattern spreads across all 32 banks
//   (linear layout would be 16-way conflicted).
// - Weights register-resident (keep-alive asm); one barrier per step.
// ---------------------------------------------------------------------------
__global__ __launch_bounds__(LTH, 2) void lstm_mfma_kernel(
    const float* __restrict__ x,     // (T, NS, IND)
    const float* __restrict__ W_ih,  // (GATES, IND)
    const float* __restrict__ W_hh,  // (GATES, HID)
    const float* __restrict__ b_ih,  // (GATES)
    const float* __restrict__ b_hh,  // (GATES)
    float* __restrict__ se,          // (NS, HID) out fp32
    _Float16* __restrict__ se16)     // (NS, HID) out f16
{
    __shared__ __align__(16) _Float16 sA[2][16][HID];          // 8 KB, swizzled
    __shared__ __align__(16) _Float16 sX[T_STEPS][16][XPAD];   // 31.25 KB

    const int tid    = threadIdx.x;
    const int w      = tid >> 6;       // wave 0..7
    const int l      = tid & 63;
    const int lane16 = l & 15;
    const int lgrp   = l >> 4;         // 0..3 (MFMA fragment k-group)
    const int n0     = blockIdx.x * LROWS;

    // ---- prologue: W -> f16 fragments in registers (static all 50 steps)
    // gate col gi = 128*gg + 16*w + lane16
    // Bx[gg]:     k = lgrp*4 + j         (x part, K=16, 16x16x16 frag)
    // Bh[gg][kf]: k = kf*32 + lgrp*8 + j (h part, K=128, 16x16x32 frags)
    f16x8 Bh[4][4];
    f16x4 Bx[4];
    float bias[4];
#pragma unroll
    for (int gg = 0; gg < 4; ++gg) {
        const int gi = 128 * gg + 16 * w + lane16;
        bias[gg] = b_ih[gi] + b_hh[gi];
        f16x4 vx;
#pragma unroll
        for (int j = 0; j < 4; ++j)
            vx[j] = (_Float16)W_ih[gi * IND + lgrp * 4 + j];
        Bx[gg] = vx;
#pragma unroll
        for (int kf = 0; kf < 4; ++kf) {
            f16x8 v;
            const float* p = W_hh + gi * HID + kf * 32 + lgrp * 8;
#pragma unroll
            for (int j = 0; j < 8; ++j) v[j] = (_Float16)p[j];
            Bh[gg][kf] = v;
        }
    }
    // Opaque to the optimizer: cannot rematerialize -> stays resident.
    // ("+v" at (512,2) bounds: the proven no-spill recipe.)
#pragma unroll
    for (int gg = 0; gg < 4; ++gg) {
        asm volatile("" : "+v"(Bx[gg]));
#pragma unroll
        for (int kf = 0; kf < 4; ++kf)
            asm volatile("" : "+v"(Bh[gg][kf]));
    }

    // zero sA (h0 = 0; odd M-rows stay zero forever) and sX (odd rows zero)
    for (int i = tid; i < 2 * 16 * HID; i += LTH)
        (&sA[0][0][0])[i] = (_Float16)0.0f;
    for (int i = tid; i < T_STEPS * 16 * XPAD; i += LTH)
        (&sX[0][0][0])[i] = (_Float16)0.0f;
    __syncthreads();

    // stage ALL x once: real row r -> M-row 2r (coalesced global reads)
    for (int i = tid; i < T_STEPS * LROWS * IND; i += LTH) {
        const int t = i >> 7, e = i & 127;
        sX[t][(e >> 4) * 2][e & 15] = (_Float16)x[((size_t)t * NS + n0) * IND + e];
    }
    __syncthreads();

    // lane owns real rows 2*lgrp (C-reg 0) and 2*lgrp+1 (C-reg 2), col 16w+lane16
    const char* aread_base0 = (const char*)&sA[0][0][0] + lane16 * (HID * 2);
    const char* aread_base1 = (const char*)&sA[1][0][0] + lane16 * (HID * 2);
    const int   axor = (lane16 & 7) << 4;
    const int   hrow0 = 4 * lgrp, hrow1 = 4 * lgrp + 2;   // even M-rows
    const int   hcol2 = (16 * w + lane16) * 2;            // byte offset in row
    const int   hb0 = hrow0 * (HID * 2) + (hcol2 ^ ((hrow0 & 7) << 4));
    const int   hb1 = hrow1 * (HID * 2) + (hcol2 ^ ((hrow1 & 7) << 4));

    float c0 = 0.f, c1 = 0.f, h0 = 0.f, h1 = 0.f;

    for (int step = 0; step < T_STEPS; ++step) {
        const int cur = step & 1, nxt = cur ^ 1;
        const char* abase = cur ? aread_base1 : aread_base0;

        // x-part A fragment (read-only sX, conflict-free b64)
        f16x4 Ax = *(const f16x4*)&sX[step][lane16][lgrp * 4];

        // h-part A fragments: swizzled ds_read_b128, full 32-bank spread
        f16x8 Ah[4];
#pragma unroll
        for (int kf = 0; kf < 4; ++kf)
            Ah[kf] = *(const f16x8*)(abase + ((kf * 64 + lgrp * 16) ^ axor));

        f32x4 az0 = {bias[0], bias[0], bias[0], bias[0]};
        f32x4 az1 = {bias[1], bias[1], bias[1], bias[1]};
        f32x4 az2 = {bias[2], bias[2], bias[2], bias[2]};
        f32x4 az3 = {bias[3], bias[3], bias[3], bias[3]};
        az0 = __builtin_amdgcn_mfma_f32_16x16x16f16(Ax, Bx[0], az0, 0, 0, 0);
        az1 = __builtin_amdgcn_mfma_f32_16x16x16f16(Ax, Bx[1], az1, 0, 0, 0);
        az2 = __builtin_amdgcn_mfma_f32_16x16x16f16(Ax, Bx[2], az2, 0, 0, 0);
        az3 = __builtin_amdgcn_mfma_f32_16x16x16f16(Ax, Bx[3], az3, 0, 0, 0);
#pragma unroll
        for (int kf = 0; kf < 4; ++kf) {
            az0 = __builtin_amdgcn_mfma_f32_16x16x32_f16(Ah[kf], Bh[0][kf], az0, 0, 0, 0);
            az1 = __builtin_amdgcn_mfma_f32_16x16x32_f16(Ah[kf], Bh[1][kf], az1, 0, 0, 0);
            az2 = __builtin_amdgcn_mfma_f32_16x16x32_f16(Ah[kf], Bh[2][kf], az2, 0, 0, 0);
            az3 = __builtin_amdgcn_mfma_f32_16x16x32_f16(Ah[kf], Bh[3][kf], az3, 0, 0, 0);
        }

        // cell update on C-regs 0 and 2 (both real; no cross-lane ops)
        c0 = sigm(az1[0]) * c0 + sigm(az0[0]) * tanhf_(az2[0]);
        h0 = sigm(az3[0]) * tanhf_(c0);
        c1 = sigm(az1[2]) * c1 + sigm(az0[2]) * tanhf_(az2[2]);
        h1 = sigm(az3[2]) * tanhf_(c1);

        // write h_{t+1} (swizzled) into the other buffer; one barrier per step
        if (step + 1 < T_STEPS) {
            char* wb = (char*)(nxt ? &sA[1][0][0] : &sA[0][0][0]);
            *(_Float16*)(wb + hb0) = (_Float16)h0;
            *(_Float16*)(wb + hb1) = (_Float16)h1;
        }
        __syncthreads();
    }

    se[(n0 + 2 * lgrp) * HID + 16 * w + lane16]       = h0;
    se[(n0 + 2 * lgrp + 1) * HID + 16 * w + lane16]   = h1;
    se16[(n0 + 2 * lgrp) * HID + 16 * w + lane16]     = (_Float16)h0;
    se16[(n0 + 2 * lgrp + 1) * HID + 16 * w + lane16] = (_Float16)h1;
}

// ---------------------------------------------------------------------------
// Kernel 2: precompute sw[n] = se[n].w_att[0:H] and p2[n] = se[n].w_att[H:2H].
// ---------------------------------------------------------------------------
__global__ __launch_bounds__(256) void precompute_kernel(
    const float* __restrict__ se,     // (NS, HID)
    const float* __restrict__ w_att,  // (2H + R)
    float* __restrict__ sw,           // (NS)
    float* __restrict__ p2n)          // (NS)
{
    const int wid  = threadIdx.x >> 6;
    const int lane = threadIdx.x & 63;
    const int n    = blockIdx.x * 4 + wid;

    const float a = se[n * HID + lane];
    const float b = se[n * HID + 64 + lane];
    float d1 = a * w_att[lane]       + b * w_att[64 + lane];
    float d2 = a * w_att[HID + lane] + b * w_att[HID + 64 + lane];
#pragma unroll
    for (int d = 32; d > 0; d >>= 1) {
        d1 += __shfl_xor(d1, d);
        d2 += __shfl_xor(d2, d);
    }
    if (lane == 0) { sw[n] = d1; p2n[n] = d2; }
}

// ---------------------------------------------------------------------------
// Kernel 3: FUSED attention + combine (round-10 exact). Score phase = one 4B
// gather of precomputed sw per neighbor; weighted-sum phase = coalesced
// half-wave f16 row reads. LDS 4.6 KB -> high occupancy.
// ---------------------------------------------------------------------------
__global__ __launch_bounds__(512) void attn_fused_kernel(
    const _Float16* __restrict__ se16,   // (NS, HID) f16
    const float* __restrict__ se,        // (NS, HID) fp32 (residual)
    const int*   __restrict__ neighbors, // (RR, NS, KN)
    const float* __restrict__ rel_num,   // (RR, NS)
    const float* __restrict__ sw,        // (NS) precomputed se.w_nb
    const float* __restrict__ p2n,       // (NS) precomputed se.w_self
    const float* __restrict__ w_att,     // (2H + R)
    const float* __restrict__ b_att,     // (1)
    const float* __restrict__ w_rel,     // (H + R)
    const float* __restrict__ b_rel,     // (1)
    const float* __restrict__ w_fc1,     // (HID)
    const float* __restrict__ b_fc1,     // (1)
    float* __restrict__ out)             // (NS)
{
    __shared__ float srel[RR][HID];      // 4 KB
    __shared__ float srsc[RR];

    const int r    = threadIdx.x >> 6;   // wave = relation 0..7
    const int lane = threadIdx.x & 63;
    const int n    = blockIdx.x;
    const size_t pair = (size_t)r * NS + n;
    const f16x4* se16_4 = (const f16x4*)se16;

    int myidx = 0;
    if (lane < KN) myidx = neighbors[pair * KN + lane];

    // ---- score: one scalar gather per neighbor (zero row -> dot = 0)
    float s = 0.f;
    if (lane < KN) {
        float swv = (myidx != 0) ? sw[myidx - 1] : 0.f;
        s = swv + p2n[n] + w_att[2 * HID + r] + b_att[0];
    }
    float mx = s;
#pragma unroll
    for (int d = 16; d > 0; d >>= 1) mx = fmaxf(mx, __shfl_xor(mx, d, 32));
    float e  = __expf(s - mx);
    float sm = e;
#pragma unroll
    for (int d = 16; d > 0; d >>= 1) sm += __shfl_xor(sm, d, 32);
    float att = e * rcp_(sm);    // valid in lanes 0..31

    // ---- weighted sum: lanes as (k2 = lane>>5, c4 = lane&31)
    const int k2 = lane >> 5;
    const int c4 = lane & 31;
    float ax = 0.f, ay = 0.f, az = 0.f, aw = 0.f;
#pragma unroll
    for (int kk = 0; kk < KN / 2; ++kk) {
        const int   kq = kk * 2 + k2;
        const float av = __shfl(att, kq);
        const int  idq = __shfl(myidx, kq);
        if (idq != 0) {
            f16x4 v = se16_4[(size_t)(idq - 1) * (HID / 4) + c4];
            ax += av * (float)v[0]; ay += av * (float)v[1];
            az += av * (float)v[2]; aw += av * (float)v[3];
        }
    }
    ax += __shfl_xor(ax, 32); ay += __shfl_xor(ay, 32);
    az += __shfl_xor(az, 32); aw += __shfl_xor(aw, 32);

    const float inv = rcp_(rel_num[pair] + EPSV);
    float pr = 0.f;
    if (k2 == 0) {
        ax *= inv; ay *= inv; az *= inv; aw *= inv;
        *(float4*)&srel[r][c4 * 4] = make_float4(ax, ay, az, aw);
        pr = ax * w_rel[c4 * 4] + ay * w_rel[c4 * 4 + 1]
           + az * w_rel[c4 * 4 + 2] + aw * w_rel[c4 * 4 + 3];
    }
#pragma unroll
    for (int d = 16; d > 0; d >>= 1) pr += __shfl_xor(pr, d, 32);
    if (lane == 0) srsc[r] = pr + w_rel[HID + r] + b_rel[0];

    __syncthreads();   // the only block-wide barrier

    if (r == 0) {
        float rs[RR];
        float rmx = -1e30f;
#pragma unroll
        for (int q = 0; q < RR; ++q) {
            rs[q] = srsc[q];
            rmx = fmaxf(rmx, rs[q]);
        }
        float rsm = 0.f;
#pragma unroll
        for (int q = 0; q < RR; ++q) {
            rs[q] = __expf(rs[q] - rmx);
            rsm += rs[q];
        }
        const float invs = rcp_(rsm * (float)RR);

        float u0 = 0.f, u1 = 0.f;
#pragma unroll
        for (int q = 0; q < RR; ++q) {
            u0 += rs[q] * srel[q][lane];
            u1 += rs[q] * srel[q][64 + lane];
        }
        u0 = u0 * invs + se[n * HID + lane];
        u1 = u1 * invs + se[n * HID + 64 + lane];

        float p = u0 * w_fc1[lane] + u1 * w_fc1[64 + lane];
#pragma unroll
        for (int d = 32; d > 0; d >>= 1) p += __shfl_xor(p, d);
        if (lane == 0) out[n] = p + b_fc1[0];
    }
}

// ---------------------------------------------------------------------------
extern "C" void kernel_launch(void* const* d_in, const int* in_sizes, int n_in,
                              void* d_out, int out_size, void* d_ws, size_t ws_size,
                              hipStream_t stream) {
    const float* x      = (const float*)d_in[0];
    const int*   nbrs   = (const int*)  d_in[1];
    const float* relnum = (const float*)d_in[2];
    const float* W_ih   = (const float*)d_in[3];
    const float* W_hh   = (const float*)d_in[4];
    const float* b_ih   = (const float*)d_in[5];
    const float* b_hh   = (const float*)d_in[6];
    const float* w_att  = (const float*)d_in[7];
    const float* b_att  = (const float*)d_in[8];
    const float* w_rel  = (const float*)d_in[9];
    const float* b_rel  = (const float*)d_in[10];
    const float* w_fc1  = (const float*)d_in[11];
    const float* b_fc1  = (const float*)d_in[12];
    float* out = (float*)d_out;

    // workspace: se fp32 (1MB) | se16 f16 (512KB) | sw (8KB) | p2 (8KB)
    float*    se   = (float*)d_ws;
    _Float16* se16 = (_Float16*)(se + (size_t)NS * HID);
    float*    sw   = (float*)(se16 + (size_t)NS * HID);
    float*    p2n  = sw + NS;

    hipLaunchKernelGGL(lstm_mfma_kernel, dim3(NS / LROWS), dim3(LTH), 0, stream,
                       x, W_ih, W_hh, b_ih, b_hh, se, se16);
    hipLaunchKernelGGL(precompute_kernel, dim3(NS / 4), dim3(256), 0, stream,
                       se, w_att, sw, p2n);
    hipLaunchKernelGGL(attn_fused_kernel, dim3(NS), dim3(512), 0, stream,
                       se16, se, nbrs, relnum, sw, p2n, w_att, b_att,
                       w_rel, b_rel, w_fc1, b_fc1, out);
}